// Round 2
// baseline (408.124 us; speedup 1.0000x reference)
//
#include <hip/hip_runtime.h>

// Problem constants
#define BN   4
#define NN   128
#define INF  256
#define EF   128
#define OUTF 128
#define EPSF 1e-5f
// bf16(1e9) = 998244352.  The harness's np reference (and comparison) go
// through bf16 rounding, so write NEG in the exact value the ref carries.
#define NEGF -998244352.0f

// ---- workspace layout (float offsets) ----
constexpr size_t TRI1 = 0;            // B*N*8   tri_1 (masked)
constexpr size_t TRI2 = 4096;         // tri_2
constexpr size_t TRI3 = 8192;         // tri_3
constexpr size_t MSG1 = 12288;        // B*N*128 msg_1 (masked)
constexpr size_t MSG2 = 77824;        // msg_2 (masked)
constexpr size_t ZWU1 = 143360;       // z @ WU1 (unmasked)
constexpr size_t TRIG = 208896;       // B*8
constexpr size_t MSGG = 209920;       // B*128
constexpr size_t E1T  = 210944;       // B*N*N*8  [b][j][i][c]  (tri_e1 transposed)
constexpr size_t E2T  = 735232;       // B*N*N*8  [b][k][i][c]  (tri_e2 transposed)
constexpr size_t E3N  = 1259520;      // B*N*N*8  [b][j][k][c]  (tri_e3 natural)
constexpr size_t MSGE = 1783808;      // B*N*N*128 [b][i][j][c] (adj-masked)
constexpr size_t FLAGOFF = 10172416;  // int flag: 1 = bools are int32, 0 = bytes

// ---- output layout (float offsets): ret, msgs, tri_msgs ----
constexpr size_t O_RET = 0;
constexpr size_t O_MSG = 65536;
constexpr size_t O_TRI = 131072;

// bool arrays may arrive as 1-byte bools or int32 (harness "integer -> int").
__device__ __forceinline__ bool rdbool(const void* p, size_t idx, int isInt) {
    if (isInt) return ((const int*)p)[idx] != 0;
    return ((const unsigned char*)p)[idx] != 0;
}

// ============================================================
// Detector: mask[b=0, n=0..3] are always true (lengths >= 64).
// byte-bools  -> bytes 1..3 nonzero.
// int32-bools -> bytes 1..3 are the high bytes of mask[0][0] = 0.
// ============================================================
__global__ void k_detect(const unsigned char* __restrict__ mask, int* __restrict__ flag) {
    if (threadIdx.x == 0) {
        int bytes = (mask[1] | mask[2] | mask[3]) != 0;
        *flag = bytes ? 0 : 1;
    }
}

// ============================================================
// Kernel A: per-(b,n) z-row projections.  grid 512, block 256
// ============================================================
__global__ __launch_bounds__(256) void k_proj_z(
    const float* __restrict__ z, const void* __restrict__ mask,
    const float* __restrict__ Wt1, const float* __restrict__ Wt2, const float* __restrict__ Wt3,
    const float* __restrict__ Wm1, const float* __restrict__ Wm2, const float* __restrict__ WU1,
    float* __restrict__ ws, const int* __restrict__ flagp)
{
    int bn  = blockIdx.x;
    int tid = threadIdx.x;
    int isInt = *flagp;
    __shared__ float zr[INF];
    zr[tid] = z[(size_t)bn * INF + tid];
    __syncthreads();
    float mk = rdbool(mask, bn, isInt) ? 1.f : 0.f;
    for (int idx = tid; idx < 408; idx += 256) {
        const float* W; int c; size_t dst; int width; bool msk;
        if (idx < 8)        { W = Wt1; c = idx;       dst = TRI1 + (size_t)bn * 8;   width = 8;   msk = true;  }
        else if (idx < 16)  { W = Wt2; c = idx - 8;   dst = TRI2 + (size_t)bn * 8;   width = 8;   msk = true;  }
        else if (idx < 24)  { W = Wt3; c = idx - 16;  dst = TRI3 + (size_t)bn * 8;   width = 8;   msk = true;  }
        else if (idx < 152) { W = Wm1; c = idx - 24;  dst = MSG1 + (size_t)bn * 128; width = 128; msk = true;  }
        else if (idx < 280) { W = Wm2; c = idx - 152; dst = MSG2 + (size_t)bn * 128; width = 128; msk = true;  }
        else                { W = WU1; c = idx - 280; dst = ZWU1 + (size_t)bn * 128; width = 128; msk = false; }
        float acc = 0.f;
        #pragma unroll 8
        for (int k = 0; k < INF; k++) acc += zr[k] * W[k * width + c];
        ws[dst + c] = msk ? acc * mk : acc;
    }
}

// ============================================================
// Kernel G: graph_fts projections.  grid 4, block 256
// ============================================================
__global__ __launch_bounds__(256) void k_proj_g(
    const float* __restrict__ g, const float* __restrict__ Wg, const float* __restrict__ Wmg,
    float* __restrict__ ws)
{
    int b = blockIdx.x, tid = threadIdx.x;
    __shared__ float gr[128];
    if (tid < 128) gr[tid] = g[b * 128 + tid];
    __syncthreads();
    if (tid < 8) {
        float a = 0.f;
        for (int k = 0; k < 128; k++) a += gr[k] * Wg[k * 8 + tid];
        ws[TRIG + b * 8 + tid] = a;
    } else if (tid >= 128) {
        int c = tid - 128;
        float a = 0.f;
        for (int k = 0; k < 128; k++) a += gr[k] * Wmg[k * 128 + c];
        ws[MSGG + b * 128 + c] = a;
    }
}

// ============================================================
// Kernel B: e_dense projections (Wme GEMM + We1..3).
// block = one (b,i): 128 rows (j) x K=128.  grid 512, block 256
// ============================================================
__global__ __launch_bounds__(256) void k_proj_e(
    const float* __restrict__ e, const void* __restrict__ adj,
    const float* __restrict__ We1, const float* __restrict__ We2, const float* __restrict__ We3,
    const float* __restrict__ Wme, float* __restrict__ ws, const int* __restrict__ flagp)
{
    int bi = blockIdx.x;
    int b = bi >> 7, i = bi & 127;
    int tid = threadIdx.x;
    int isInt = *flagp;
    __shared__ float et[128 * 129];   // +1 pad
    __shared__ float Wl[16 * 128];
    const float* esrc = e + (size_t)bi * 128 * 128;
    for (int m = tid; m < 4096; m += 256) {
        float4 v = ((const float4*)esrc)[m];
        int row = m >> 5, col = (m & 31) << 2;
        float* d = &et[row * 129 + col];
        d[0] = v.x; d[1] = v.y; d[2] = v.z; d[3] = v.w;
    }
    int tc = tid & 15, tjg = tid >> 4;
    float acc[8][8];
    #pragma unroll
    for (int r = 0; r < 8; r++)
        #pragma unroll
        for (int s = 0; s < 8; s++) acc[r][s] = 0.f;

    for (int kc = 0; kc < 8; kc++) {
        __syncthreads();   // staging done / previous chunk consumed
        {
            int base = tid * 8;
            int kk = base >> 7, cc = base & 127;
            const float4* src = (const float4*)&Wme[(size_t)(kc * 16 + kk) * 128 + cc];
            float4 v0 = src[0], v1 = src[1];
            float* d = &Wl[base];
            d[0] = v0.x; d[1] = v0.y; d[2] = v0.z; d[3] = v0.w;
            d[4] = v1.x; d[5] = v1.y; d[6] = v1.z; d[7] = v1.w;
        }
        __syncthreads();
        #pragma unroll
        for (int kk = 0; kk < 16; kk++) {
            int k = kc * 16 + kk;
            float a[8], w[8];
            #pragma unroll
            for (int r = 0; r < 8; r++) a[r] = et[(tjg * 8 + r) * 129 + k];
            #pragma unroll
            for (int s = 0; s < 8; s++) w[s] = Wl[kk * 128 + tc * 8 + s];
            #pragma unroll
            for (int r = 0; r < 8; r++)
                #pragma unroll
                for (int s = 0; s < 8; s++) acc[r][s] += a[r] * w[s];
        }
    }
    // msg_e = adj ? e@Wme : 0   stored [b][i][j][c]
    #pragma unroll
    for (int r = 0; r < 8; r++) {
        int j = tjg * 8 + r;
        float am = rdbool(adj, (size_t)bi * 128 + j, isInt) ? 1.f : 0.f;
        float* dst = ws + MSGE + ((size_t)bi * 128 + j) * 128 + tc * 8;
        #pragma unroll
        for (int s = 0; s < 8; s++) dst[s] = acc[r][s] * am;
    }
    // tri_e1/2/3 (unmasked), 24 cols
    for (int m = tid; m < 3072; m += 256) {
        int row = m / 24, col = m - row * 24;
        const float* W = (col < 8) ? We1 : (col < 16 ? We2 : We3);
        int c = col & 7;
        float a = 0.f;
        #pragma unroll 8
        for (int k = 0; k < 128; k++) a += et[row * 129 + k] * W[k * 8 + c];
        size_t dst;
        if (col < 8)       dst = E1T + ((size_t)(b * 128 + row) * 128 + i) * 8 + c; // [b][j=row][i][c]
        else if (col < 16) dst = E2T + ((size_t)(b * 128 + row) * 128 + i) * 8 + c; // [b][k=row][i][c]
        else               dst = E3N + ((size_t)bi * 128 + row) * 8 + c;            // [b][j=i][k=row][c]
        ws[dst] = a;
    }
}

// ============================================================
// Kernel C: triplet max-plus pooling + relu(pooled @ WU3).
// grid (8,8,4) = (jt, kt, b), block 256; 16x16 (j,k) tile
// ============================================================
__global__ __launch_bounds__(256) void k_triplet(
    const float* __restrict__ ws, const void* __restrict__ mask,
    const float* __restrict__ WU3, float* __restrict__ out, const int* __restrict__ flagp)
{
    int j0 = blockIdx.x * 16, k0 = blockIdx.y * 16, b = blockIdx.z;
    int tid = threadIdx.x;
    int isInt = *flagp;
    __shared__ float Pl[16 * 264];          // [tj][i-chunk*8+c], padded stride
    __shared__ float Ql[16 * 264];
    __shared__ float pooled[16 * 16 * 8];
    __shared__ float WU3l[8 * 128];
    __shared__ unsigned char mloc[128];
    if (tid < 128) mloc[tid] = rdbool(mask, b * 128 + tid, isInt) ? 1 : 0;
    for (int m = tid; m < 1024; m += 256) WU3l[m] = WU3[m];

    int tj = tid >> 4, tk = tid & 15;
    float accM[8], accU[8];
    #pragma unroll
    for (int c = 0; c < 8; c++) { accM[c] = NEGF; accU[c] = NEGF; }

    int rr = tid >> 4;
    int base = (tid & 15) * 16;
    for (int i0 = 0; i0 < 128; i0 += 32) {
        __syncthreads();
        {
            const float4* e1 = (const float4*)(ws + E1T + ((size_t)(b * 128 + j0 + rr) * 128 + i0) * 8 + base);
            const float4* t1 = (const float4*)(ws + TRI1 + ((size_t)b * 128 + i0) * 8 + base);
            const float4* e2 = (const float4*)(ws + E2T + ((size_t)(b * 128 + k0 + rr) * 128 + i0) * 8 + base);
            float* pd = &Pl[rr * 264 + base];
            float* qd = &Ql[rr * 264 + base];
            #pragma unroll
            for (int t = 0; t < 4; t++) {
                float4 a = e1[t], bb = t1[t], q = e2[t];
                pd[t * 4 + 0] = a.x + bb.x; pd[t * 4 + 1] = a.y + bb.y;
                pd[t * 4 + 2] = a.z + bb.z; pd[t * 4 + 3] = a.w + bb.w;
                qd[t * 4 + 0] = q.x; qd[t * 4 + 1] = q.y;
                qd[t * 4 + 2] = q.z; qd[t * 4 + 3] = q.w;
            }
        }
        __syncthreads();
        for (int ii = 0; ii < 32; ii++) {
            bool m_i = mloc[i0 + ii] != 0;     // wave-uniform
            const float* pp = &Pl[tj * 264 + ii * 8];
            const float* qq = &Ql[tk * 264 + ii * 8];
            if (m_i) {
                #pragma unroll
                for (int c = 0; c < 8; c++) accM[c] = fmaxf(accM[c], pp[c] + qq[c]);
            } else {
                #pragma unroll
                for (int c = 0; c < 8; c++) accU[c] = fmaxf(accU[c], pp[c] + qq[c]);
            }
        }
    }
    {
        bool mj = mloc[j0 + tj] != 0, mk2 = mloc[k0 + tk] != 0;
        bool all_i = mj || mk2;   // allowed set = all i, else only masked i
        const float* t2 = ws + TRI2 + (size_t)(b * 128 + j0 + tj) * 8;
        const float* t3 = ws + TRI3 + (size_t)(b * 128 + k0 + tk) * 8;
        const float* e3 = ws + E3N + ((size_t)(b * 128 + j0 + tj) * 128 + (k0 + tk)) * 8;
        const float* tg = ws + TRIG + (size_t)b * 8;
        float* pdst = &pooled[(tj * 16 + tk) * 8];
        #pragma unroll
        for (int c = 0; c < 8; c++) {
            float mx = all_i ? fmaxf(accM[c], accU[c]) : accM[c];
            pdst[c] = mx + t2[c] + t3[c] + e3[c] + tg[c];
        }
    }
    __syncthreads();
    int col = tid & 127, ph = tid >> 7;
    for (int p = ph; p < 256; p += 2) {
        const float* pl = &pooled[p * 8];
        float s = 0.f;
        #pragma unroll
        for (int c = 0; c < 8; c++) s += pl[c] * WU3l[c * 128 + col];
        s = fmaxf(s, 0.f);
        int tjp = p >> 4, tkp = p & 15;
        out[O_TRI + ((size_t)(b * 128 + j0 + tjp) * 128 + (k0 + tkp)) * 128 + col] = s;
    }
}

// ============================================================
// Kernel D: pairwise MLP + masked max over i.
// block = one (b,j): rows i=0..127.  grid 512, block 256
// ============================================================
__global__ __launch_bounds__(256) void k_pair_mlp(
    const float* __restrict__ ws, const void* __restrict__ adj,
    const float* __restrict__ ln1s, const float* __restrict__ ln1o,
    const float* __restrict__ W1,
    const float* __restrict__ ln2s, const float* __restrict__ ln2o,
    const float* __restrict__ W2,
    float* __restrict__ out, const int* __restrict__ flagp)
{
    int bj = blockIdx.x;
    int b = bj >> 7, j = bj & 127;
    int tid = threadIdx.x;
    int isInt = *flagp;
    __shared__ float T[128 * 129];
    __shared__ float Wl[16 * 128];
    __shared__ float mu[128], inv[128];
    __shared__ float pw[4 * 128];

    const float* msg1 = ws + MSG1 + (size_t)bj * 128;
    const float* msgg = ws + MSGG + (size_t)b * 128;
    // T[i][c] = msg2[b,i,c] + msge[b,i,j,c] + msg1[b,j,c] + msgg[b,c]
    for (int m = tid; m < 16384; m += 256) {
        int i = m >> 7, c = m & 127;
        T[i * 129 + c] = ws[MSG2 + ((size_t)b * 128 + i) * 128 + c]
                       + ws[MSGE + (((size_t)b * 128 + i) * 128 + j) * 128 + c]
                       + msg1[c] + msgg[c];
    }
    __syncthreads();
    if (tid < 128) {
        float s = 0.f, ss = 0.f;
        for (int c = 0; c < 128; c++) { float v = T[tid * 129 + c]; s += v; ss += v * v; }
        float m_ = s * (1.f / 128), v_ = ss * (1.f / 128) - m_ * m_;
        mu[tid] = m_; inv[tid] = rsqrtf(v_ + EPSF);
    }
    __syncthreads();
    for (int m = tid; m < 16384; m += 256) {
        int i = m >> 7, c = m & 127;
        float v = ln1s[c] * inv[i] * (T[i * 129 + c] - mu[i]) + ln1o[c];
        T[i * 129 + c] = fmaxf(v, 0.f);
    }

    int tc = tid & 15, tjg = tid >> 4;
    float acc[8][8];
    #pragma unroll
    for (int r = 0; r < 8; r++)
        #pragma unroll
        for (int s = 0; s < 8; s++) acc[r][s] = 0.f;

    // ---- GEMM1: relu(LN1(T)) @ W1 ----
    for (int kc = 0; kc < 8; kc++) {
        __syncthreads();
        {
            int base = tid * 8;
            int kk = base >> 7, cc = base & 127;
            const float4* src = (const float4*)&W1[(size_t)(kc * 16 + kk) * 128 + cc];
            float4 v0 = src[0], v1 = src[1];
            float* d = &Wl[base];
            d[0] = v0.x; d[1] = v0.y; d[2] = v0.z; d[3] = v0.w;
            d[4] = v1.x; d[5] = v1.y; d[6] = v1.z; d[7] = v1.w;
        }
        __syncthreads();
        #pragma unroll
        for (int kk = 0; kk < 16; kk++) {
            int k = kc * 16 + kk;
            float a[8], w[8];
            #pragma unroll
            for (int r = 0; r < 8; r++) a[r] = T[(tjg * 8 + r) * 129 + k];
            #pragma unroll
            for (int s = 0; s < 8; s++) w[s] = Wl[kk * 128 + tc * 8 + s];
            #pragma unroll
            for (int r = 0; r < 8; r++)
                #pragma unroll
                for (int s = 0; s < 8; s++) acc[r][s] += a[r] * w[s];
        }
    }
    // ---- LN2 stats via shuffle over the 16 lanes sharing a row group ----
    float mu2[8], inv2[8];
    #pragma unroll
    for (int r = 0; r < 8; r++) {
        float s = 0.f, ss = 0.f;
        #pragma unroll
        for (int sx = 0; sx < 8; sx++) { float v = acc[r][sx]; s += v; ss += v * v; }
        for (int d = 1; d < 16; d <<= 1) { s += __shfl_xor(s, d, 64); ss += __shfl_xor(ss, d, 64); }
        float m_ = s * (1.f / 128), v_ = ss * (1.f / 128) - m_ * m_;
        mu2[r] = m_; inv2[r] = rsqrtf(v_ + EPSF);
    }
    __syncthreads();   // all GEMM1 reads of T done before overwrite
    #pragma unroll
    for (int r = 0; r < 8; r++)
        #pragma unroll
        for (int sx = 0; sx < 8; sx++) {
            int i = tjg * 8 + r, c = tc * 8 + sx;
            float v = ln2s[c] * inv2[r] * (acc[r][sx] - mu2[r]) + ln2o[c];
            T[i * 129 + c] = fmaxf(v, 0.f);
            acc[r][sx] = 0.f;
        }
    // ---- GEMM2: relu(LN2(x1)) @ W2 ----
    for (int kc = 0; kc < 8; kc++) {
        __syncthreads();
        {
            int base = tid * 8;
            int kk = base >> 7, cc = base & 127;
            const float4* src = (const float4*)&W2[(size_t)(kc * 16 + kk) * 128 + cc];
            float4 v0 = src[0], v1 = src[1];
            float* d = &Wl[base];
            d[0] = v0.x; d[1] = v0.y; d[2] = v0.z; d[3] = v0.w;
            d[4] = v1.x; d[5] = v1.y; d[6] = v1.z; d[7] = v1.w;
        }
        __syncthreads();
        #pragma unroll
        for (int kk = 0; kk < 16; kk++) {
            int k = kc * 16 + kk;
            float a[8], w[8];
            #pragma unroll
            for (int r = 0; r < 8; r++) a[r] = T[(tjg * 8 + r) * 129 + k];
            #pragma unroll
            for (int s = 0; s < 8; s++) w[s] = Wl[kk * 128 + tc * 8 + s];
            #pragma unroll
            for (int r = 0; r < 8; r++)
                #pragma unroll
                for (int s = 0; s < 8; s++) acc[r][s] += a[r] * w[s];
        }
    }
    // ---- adj mask + max over i (rows), output msgs[b,j,:] ----
    float am[8];
    #pragma unroll
    for (int r = 0; r < 8; r++)
        am[r] = rdbool(adj, ((size_t)b * 128 + tjg * 8 + r) * 128 + j, isInt) ? 1.f : 0.f;
    float pmax[8];
    #pragma unroll
    for (int sx = 0; sx < 8; sx++) {
        float pv = NEGF;
        #pragma unroll
        for (int r = 0; r < 8; r++) pv = (am[r] > 0.f) ? fmaxf(pv, acc[r][sx]) : pv;
        pv = fmaxf(pv, __shfl_xor(pv, 16, 64));   // combine tjg groups within wave
        pv = fmaxf(pv, __shfl_xor(pv, 32, 64));
        pmax[sx] = pv;
    }
    int wave = tid >> 6;
    if ((tid & 63) < 16) {
        #pragma unroll
        for (int sx = 0; sx < 8; sx++) pw[wave * 128 + tc * 8 + sx] = pmax[sx];
    }
    __syncthreads();
    if (tid < 128) {
        float mx = fmaxf(fmaxf(pw[tid], pw[128 + tid]), fmaxf(pw[256 + tid], pw[384 + tid]));
        out[O_MSG + (size_t)bj * 128 + tid] = mx;
    }
}

// ============================================================
// Kernel F: ret = LN(z@WU1 + msgs@WU2).  grid 512, block 128
// ============================================================
__global__ __launch_bounds__(128) void k_final(
    const float* __restrict__ ws, const float* __restrict__ WU2,
    const float* __restrict__ lnfs, const float* __restrict__ lnfo,
    float* __restrict__ out)
{
    int bn = blockIdx.x, tid = threadIdx.x;
    __shared__ float mrow[128];
    __shared__ float red[4];
    mrow[tid] = out[O_MSG + (size_t)bn * 128 + tid];
    __syncthreads();
    float y = ws[ZWU1 + (size_t)bn * 128 + tid];
    #pragma unroll 8
    for (int k = 0; k < 128; k++) y += mrow[k] * WU2[k * 128 + tid];
    float s = y, ss = y * y;
    for (int d = 1; d < 64; d <<= 1) { s += __shfl_xor(s, d, 64); ss += __shfl_xor(ss, d, 64); }
    if ((tid & 63) == 0) { red[(tid >> 6) * 2] = s; red[(tid >> 6) * 2 + 1] = ss; }
    __syncthreads();
    float S = red[0] + red[2], SS = red[1] + red[3];
    float m_ = S * (1.f / 128), v_ = SS * (1.f / 128) - m_ * m_;
    float r = rsqrtf(v_ + EPSF);
    out[O_RET + (size_t)bn * 128 + tid] = lnfs[tid] * r * (y - m_) + lnfo[tid];
}

// ============================================================
extern "C" void kernel_launch(void* const* d_in, const int* in_sizes, int n_in,
                              void* d_out, int out_size, void* d_ws, size_t ws_size,
                              hipStream_t stream)
{
    const float* z    = (const float*)d_in[0];
    const float* e    = (const float*)d_in[1];
    const float* gf   = (const float*)d_in[2];
    const void*  mask = d_in[3];   // bool: byte or int32, detected at runtime
    const void*  adj  = d_in[4];
    const float* Wt1 = (const float*)d_in[5];
    const float* Wt2 = (const float*)d_in[6];
    const float* Wt3 = (const float*)d_in[7];
    const float* We1 = (const float*)d_in[8];
    const float* We2 = (const float*)d_in[9];
    const float* We3 = (const float*)d_in[10];
    const float* Wg  = (const float*)d_in[11];
    const float* Wm1 = (const float*)d_in[12];
    const float* Wm2 = (const float*)d_in[13];
    const float* Wme = (const float*)d_in[14];
    const float* Wmg = (const float*)d_in[15];
    const float* ln1s = (const float*)d_in[16];
    const float* ln1o = (const float*)d_in[17];
    const float* W1   = (const float*)d_in[18];
    const float* ln2s = (const float*)d_in[19];
    const float* ln2o = (const float*)d_in[20];
    const float* W2   = (const float*)d_in[21];
    const float* WU1  = (const float*)d_in[22];
    const float* WU2  = (const float*)d_in[23];
    const float* WU3  = (const float*)d_in[24];
    const float* lnfs = (const float*)d_in[25];
    const float* lnfo = (const float*)d_in[26];
    float* out = (float*)d_out;
    float* ws  = (float*)d_ws;
    int* flag  = (int*)(ws + FLAGOFF);

    hipLaunchKernelGGL(k_detect, dim3(1), dim3(64), 0, stream,
                       (const unsigned char*)mask, flag);
    hipLaunchKernelGGL(k_proj_z, dim3(512), dim3(256), 0, stream,
                       z, mask, Wt1, Wt2, Wt3, Wm1, Wm2, WU1, ws, flag);
    hipLaunchKernelGGL(k_proj_g, dim3(4), dim3(256), 0, stream, gf, Wg, Wmg, ws);
    hipLaunchKernelGGL(k_proj_e, dim3(512), dim3(256), 0, stream,
                       e, adj, We1, We2, We3, Wme, ws, flag);
    hipLaunchKernelGGL(k_triplet, dim3(8, 8, 4), dim3(256), 0, stream, ws, mask, WU3, out, flag);
    hipLaunchKernelGGL(k_pair_mlp, dim3(512), dim3(256), 0, stream,
                       ws, adj, ln1s, ln1o, W1, ln2s, ln2o, W2, out, flag);
    hipLaunchKernelGGL(k_final, dim3(512), dim3(128), 0, stream, ws, WU2, lnfs, lnfo, out);
}

// Round 3
// 259.480 us; speedup vs baseline: 1.5729x; 1.5729x over previous
//
#include <hip/hip_runtime.h>

// Problem constants
#define BN   4
#define NN   128
#define INF  256
#define EF   128
#define OUTF 128
#define EPSF 1e-5f
#define NEGF -998244352.0f   // bf16(1e9); matches the bf16-rounded np reference

typedef __attribute__((ext_vector_type(8))) short short8;
typedef __attribute__((ext_vector_type(4))) float f32x4;

#define MFMA16(a, b, c) __builtin_amdgcn_mfma_f32_16x16x32_bf16(a, b, c, 0, 0, 0)

// fp32 -> bf16 round-to-nearest-even
__device__ __forceinline__ unsigned short f2bf(float f) {
    unsigned u = __float_as_uint(f);
    u += 0x7fffu + ((u >> 16) & 1u);
    return (unsigned short)(u >> 16);
}
__device__ __forceinline__ unsigned pack2(float a, float b) {
    return (unsigned)f2bf(a) | ((unsigned)f2bf(b) << 16);
}

// ---- workspace layout (float offsets) ----
constexpr size_t TRI1 = 0;            // B*N*8   tri_1 (masked)
constexpr size_t TRI2 = 4096;
constexpr size_t TRI3 = 8192;
constexpr size_t MSG1 = 12288;        // B*N*128 msg_1 (masked)
constexpr size_t MSG2 = 77824;
constexpr size_t ZWU1 = 143360;
constexpr size_t TRIG = 208896;       // B*8
constexpr size_t MSGG = 209920;       // B*128
constexpr size_t E1T  = 210944;       // B*N*N*8  [b][j][i][c]
constexpr size_t E2T  = 735232;       // B*N*N*8  [b][k][i][c]
constexpr size_t E3N  = 1259520;      // B*N*N*8  [b][j][k][c]
constexpr size_t MSGE = 1783808;      // B*N*N*128 [b][i][j][c]
constexpr size_t FLAGOFF = 10172416;  // int flag
constexpr size_t PREPF   = 10172420;  // bf16 prepped weights (ushort region)

// prep region offsets (ushort units)
constexpr int W1T_OFF  = 0;       // [n][k] 128x128
constexpr int W2T_OFF  = 16384;
constexpr int WMET_OFF = 32768;
constexpr int WET_OFF  = 49152;   // [n][k] 32x128 packed We1|We2|We3|0

// ---- output layout (float offsets): ret, msgs, tri_msgs ----
constexpr size_t O_RET = 0;
constexpr size_t O_MSG = 65536;
constexpr size_t O_TRI = 131072;

__device__ __forceinline__ bool rdbool(const void* p, size_t idx, int isInt) {
    if (isInt) return ((const int*)p)[idx] != 0;
    return ((const unsigned char*)p)[idx] != 0;
}

__global__ void k_detect(const unsigned char* __restrict__ mask, int* __restrict__ flag) {
    if (threadIdx.x == 0) {
        int bytes = (mask[1] | mask[2] | mask[3]) != 0;
        *flag = bytes ? 0 : 1;
    }
}

// ============================================================
// k_prep: bf16 transposed weights.  grid 208, block 256
// ============================================================
__global__ __launch_bounds__(256) void k_prep(
    const float* __restrict__ W1, const float* __restrict__ W2, const float* __restrict__ Wme,
    const float* __restrict__ We1, const float* __restrict__ We2, const float* __restrict__ We3,
    unsigned short* __restrict__ prep)
{
    int idx = blockIdx.x * 256 + threadIdx.x;
    if (idx >= 53248) return;
    if (idx < 49152) {
        const float* W = (idx < 16384) ? W1 : (idx < 32768 ? W2 : Wme);
        int i2 = idx & 16383;
        int n = i2 >> 7, k = i2 & 127;
        prep[idx] = f2bf(W[k * 128 + n]);
    } else {
        int i2 = idx - 49152;
        int n = i2 >> 7, k = i2 & 127;
        float v = 0.f;
        if (n < 8)       v = We1[k * 8 + n];
        else if (n < 16) v = We2[k * 8 + (n - 8)];
        else if (n < 24) v = We3[k * 8 + (n - 16)];
        prep[idx] = f2bf(v);
    }
}

// ============================================================
// Kernel A: per-(b,n) z-row projections.  grid 512, block 256
// ============================================================
__global__ __launch_bounds__(256) void k_proj_z(
    const float* __restrict__ z, const void* __restrict__ mask,
    const float* __restrict__ Wt1, const float* __restrict__ Wt2, const float* __restrict__ Wt3,
    const float* __restrict__ Wm1, const float* __restrict__ Wm2, const float* __restrict__ WU1,
    float* __restrict__ ws, const int* __restrict__ flagp)
{
    int bn  = blockIdx.x;
    int tid = threadIdx.x;
    int isInt = *flagp;
    __shared__ float zr[INF];
    zr[tid] = z[(size_t)bn * INF + tid];
    __syncthreads();
    float mk = rdbool(mask, bn, isInt) ? 1.f : 0.f;
    for (int idx = tid; idx < 408; idx += 256) {
        const float* W; int c; size_t dst; int width; bool msk;
        if (idx < 8)        { W = Wt1; c = idx;       dst = TRI1 + (size_t)bn * 8;   width = 8;   msk = true;  }
        else if (idx < 16)  { W = Wt2; c = idx - 8;   dst = TRI2 + (size_t)bn * 8;   width = 8;   msk = true;  }
        else if (idx < 24)  { W = Wt3; c = idx - 16;  dst = TRI3 + (size_t)bn * 8;   width = 8;   msk = true;  }
        else if (idx < 152) { W = Wm1; c = idx - 24;  dst = MSG1 + (size_t)bn * 128; width = 128; msk = true;  }
        else if (idx < 280) { W = Wm2; c = idx - 152; dst = MSG2 + (size_t)bn * 128; width = 128; msk = true;  }
        else                { W = WU1; c = idx - 280; dst = ZWU1 + (size_t)bn * 128; width = 128; msk = false; }
        float acc = 0.f;
        #pragma unroll 8
        for (int k = 0; k < INF; k++) acc += zr[k] * W[k * width + c];
        ws[dst + c] = msk ? acc * mk : acc;
    }
}

// ============================================================
// Kernel G: graph_fts projections.  grid 4, block 256
// ============================================================
__global__ __launch_bounds__(256) void k_proj_g(
    const float* __restrict__ g, const float* __restrict__ Wg, const float* __restrict__ Wmg,
    float* __restrict__ ws)
{
    int b = blockIdx.x, tid = threadIdx.x;
    __shared__ float gr[128];
    if (tid < 128) gr[tid] = g[b * 128 + tid];
    __syncthreads();
    if (tid < 8) {
        float a = 0.f;
        for (int k = 0; k < 128; k++) a += gr[k] * Wg[k * 8 + tid];
        ws[TRIG + b * 8 + tid] = a;
    } else if (tid >= 128) {
        int c = tid - 128;
        float a = 0.f;
        for (int k = 0; k < 128; k++) a += gr[k] * Wmg[k * 128 + c];
        ws[MSGG + b * 128 + c] = a;
    }
}

// ============================================================
// Kernel B (MFMA): e projections.  block = one (b,i).  grid 512, block 256
// ============================================================
__global__ __launch_bounds__(256) void k_proj_e(
    const float* __restrict__ e, const void* __restrict__ adj,
    const unsigned short* __restrict__ prep,
    float* __restrict__ ws, const int* __restrict__ flagp)
{
    int bi = blockIdx.x;
    int b = bi >> 7, i = bi & 127;
    int tid = threadIdx.x;
    int isInt = *flagp;
    __shared__ __align__(16) unsigned short Ab[128 * 136];   // e-tile bf16
    __shared__ __align__(16) unsigned short WL[128 * 136];   // Wme^T bf16
    __shared__ __align__(16) unsigned short WeL[32 * 136];   // packed We^T bf16

    // stage e rows -> bf16
    {
        int r = tid >> 1, h = tid & 1;
        const float4* ep = (const float4*)(e + (size_t)bi * 16384 + (size_t)r * 128 + h * 64);
        unsigned* dst = (unsigned*)&Ab[r * 136 + h * 64];
        #pragma unroll
        for (int q2 = 0; q2 < 16; q2++) {
            float4 v = ep[q2];
            dst[q2 * 2]     = pack2(v.x, v.y);
            dst[q2 * 2 + 1] = pack2(v.z, v.w);
        }
    }
    // stage Wme^T
    #pragma unroll
    for (int q2 = 0; q2 < 8; q2++) {
        int m = q2 * 256 + tid;
        int row = m >> 4, cc = (m & 15) * 8;
        *(short8*)&WL[row * 136 + cc] = *(const short8*)&prep[WMET_OFF + m * 8];
    }
    // stage We^T (32 rows)
    #pragma unroll
    for (int q2 = 0; q2 < 2; q2++) {
        int m = q2 * 256 + tid;
        int row = m >> 4, cc = (m & 15) * 8;
        *(short8*)&WeL[row * 136 + cc] = *(const short8*)&prep[WET_OFF + m * 8];
    }
    __syncthreads();

    int lane = tid & 63, w = tid >> 6, q = lane >> 4, n = lane & 15;

    // GEMM: msg_e pre-mask = E @ Wme  (wave w: rows 32w..32w+31, all 128 cols)
    f32x4 acc[2][8];
    #pragma unroll
    for (int rt = 0; rt < 2; rt++)
        #pragma unroll
        for (int t = 0; t < 8; t++) acc[rt][t] = 0.f;
    #pragma unroll
    for (int ks = 0; ks < 4; ks++) {
        int k0 = ks * 32 + q * 8;
        short8 a0 = *(const short8*)&Ab[(32 * w + n) * 136 + k0];
        short8 a1 = *(const short8*)&Ab[(32 * w + 16 + n) * 136 + k0];
        #pragma unroll
        for (int t = 0; t < 8; t++) {
            short8 bt = *(const short8*)&WL[(16 * t + n) * 136 + k0];
            acc[0][t] = MFMA16(a0, bt, acc[0][t]);
            acc[1][t] = MFMA16(a1, bt, acc[1][t]);
        }
    }
    // store adj-masked msg_e  [b][i][j][c]
    #pragma unroll
    for (int rt = 0; rt < 2; rt++)
        #pragma unroll
        for (int reg = 0; reg < 4; reg++) {
            int row = 32 * w + 16 * rt + 4 * q + reg;
            float am = rdbool(adj, (size_t)bi * 128 + row, isInt) ? 1.f : 0.f;
            float* dst = ws + MSGE + ((size_t)bi * 128 + row) * 128;
            #pragma unroll
            for (int t = 0; t < 8; t++) dst[16 * t + n] = acc[rt][t][reg] * am;
        }

    // GEMM: tri_e (packed 32 cols: We1|We2|We3|pad)
    f32x4 ac2[2][2];
    #pragma unroll
    for (int rt = 0; rt < 2; rt++)
        #pragma unroll
        for (int t = 0; t < 2; t++) ac2[rt][t] = 0.f;
    #pragma unroll
    for (int ks = 0; ks < 4; ks++) {
        int k0 = ks * 32 + q * 8;
        short8 a0 = *(const short8*)&Ab[(32 * w + n) * 136 + k0];
        short8 a1 = *(const short8*)&Ab[(32 * w + 16 + n) * 136 + k0];
        #pragma unroll
        for (int t = 0; t < 2; t++) {
            short8 bt = *(const short8*)&WeL[(16 * t + n) * 136 + k0];
            ac2[0][t] = MFMA16(a0, bt, ac2[0][t]);
            ac2[1][t] = MFMA16(a1, bt, ac2[1][t]);
        }
    }
    // scatter tri_e1/e2/e3
    #pragma unroll
    for (int rt = 0; rt < 2; rt++)
        #pragma unroll
        for (int reg = 0; reg < 4; reg++) {
            int row = 32 * w + 16 * rt + 4 * q + reg;   // j (or k) index
            // t=0: cols 0..15 -> We1 (c=n<8) / We2 (c=n-8)
            float v0 = ac2[rt][0][reg];
            if (n < 8) ws[E1T + ((size_t)(b * 128 + row) * 128 + i) * 8 + n] = v0;
            else       ws[E2T + ((size_t)(b * 128 + row) * 128 + i) * 8 + (n - 8)] = v0;
            // t=1: cols 16..23 -> We3
            if (n < 8) ws[E3N + ((size_t)bi * 128 + row) * 8 + n] = ac2[rt][1][reg];
        }
}

// ============================================================
// Kernel C: triplet max-plus pooling + relu(pooled @ WU3).
// grid (8,8,4), block 256; 16x16 (j,k) tile
// ============================================================
__global__ __launch_bounds__(256) void k_triplet(
    const float* __restrict__ ws, const void* __restrict__ mask,
    const float* __restrict__ WU3, float* __restrict__ out, const int* __restrict__ flagp)
{
    int j0 = blockIdx.x * 16, k0 = blockIdx.y * 16, b = blockIdx.z;
    int tid = threadIdx.x;
    int isInt = *flagp;
    __shared__ float Pl[16 * 264];
    __shared__ float Ql[16 * 264];
    __shared__ float pooled[16 * 16 * 8];
    __shared__ float WU3l[8 * 128];
    __shared__ unsigned char mloc[128];
    if (tid < 128) mloc[tid] = rdbool(mask, b * 128 + tid, isInt) ? 1 : 0;
    for (int m = tid; m < 1024; m += 256) WU3l[m] = WU3[m];

    int tj = tid >> 4, tk = tid & 15;
    float accM[8], accU[8];
    #pragma unroll
    for (int c = 0; c < 8; c++) { accM[c] = NEGF; accU[c] = NEGF; }

    int rr = tid >> 4;
    int base = (tid & 15) * 16;
    for (int i0 = 0; i0 < 128; i0 += 32) {
        __syncthreads();
        {
            const float4* e1 = (const float4*)(ws + E1T + ((size_t)(b * 128 + j0 + rr) * 128 + i0) * 8 + base);
            const float4* t1 = (const float4*)(ws + TRI1 + ((size_t)b * 128 + i0) * 8 + base);
            const float4* e2 = (const float4*)(ws + E2T + ((size_t)(b * 128 + k0 + rr) * 128 + i0) * 8 + base);
            float* pd = &Pl[rr * 264 + base];
            float* qd = &Ql[rr * 264 + base];
            #pragma unroll
            for (int t = 0; t < 4; t++) {
                float4 a = e1[t], bb = t1[t], qv = e2[t];
                pd[t * 4 + 0] = a.x + bb.x; pd[t * 4 + 1] = a.y + bb.y;
                pd[t * 4 + 2] = a.z + bb.z; pd[t * 4 + 3] = a.w + bb.w;
                qd[t * 4 + 0] = qv.x; qd[t * 4 + 1] = qv.y;
                qd[t * 4 + 2] = qv.z; qd[t * 4 + 3] = qv.w;
            }
        }
        __syncthreads();
        for (int ii = 0; ii < 32; ii++) {
            bool m_i = mloc[i0 + ii] != 0;
            const float* pp = &Pl[tj * 264 + ii * 8];
            const float* qq = &Ql[tk * 264 + ii * 8];
            if (m_i) {
                #pragma unroll
                for (int c = 0; c < 8; c++) accM[c] = fmaxf(accM[c], pp[c] + qq[c]);
            } else {
                #pragma unroll
                for (int c = 0; c < 8; c++) accU[c] = fmaxf(accU[c], pp[c] + qq[c]);
            }
        }
    }
    {
        bool mj = mloc[j0 + tj] != 0, mk2 = mloc[k0 + tk] != 0;
        bool all_i = mj || mk2;
        const float* t2 = ws + TRI2 + (size_t)(b * 128 + j0 + tj) * 8;
        const float* t3 = ws + TRI3 + (size_t)(b * 128 + k0 + tk) * 8;
        const float* e3 = ws + E3N + ((size_t)(b * 128 + j0 + tj) * 128 + (k0 + tk)) * 8;
        const float* tg = ws + TRIG + (size_t)b * 8;
        float* pdst = &pooled[(tj * 16 + tk) * 8];
        #pragma unroll
        for (int c = 0; c < 8; c++) {
            float mx = all_i ? fmaxf(accM[c], accU[c]) : accM[c];
            pdst[c] = mx + t2[c] + t3[c] + e3[c] + tg[c];
        }
    }
    __syncthreads();
    int col = tid & 127, ph = tid >> 7;
    for (int p = ph; p < 256; p += 2) {
        const float* pl = &pooled[p * 8];
        float s = 0.f;
        #pragma unroll
        for (int c = 0; c < 8; c++) s += pl[c] * WU3l[c * 128 + col];
        s = fmaxf(s, 0.f);
        int tjp = p >> 4, tkp = p & 15;
        out[O_TRI + ((size_t)(b * 128 + j0 + tjp) * 128 + (k0 + tkp)) * 128 + col] = s;
    }
}

// ============================================================
// Kernel D (MFMA): pairwise MLP + masked max over i.
// block = one (b,j).  grid 512, block 256
// ============================================================
__global__ __launch_bounds__(256) void k_pair_mlp(
    const float* __restrict__ ws, const void* __restrict__ adj,
    const float* __restrict__ ln1s, const float* __restrict__ ln1o,
    const float* __restrict__ ln2s, const float* __restrict__ ln2o,
    const unsigned short* __restrict__ prep,
    float* __restrict__ out, const int* __restrict__ flagp)
{
    int bj = blockIdx.x;
    int b = bj >> 7, j = bj & 127;
    int tid = threadIdx.x;
    int isInt = *flagp;
    __shared__ __align__(16) unsigned short Ab[128 * 136];
    __shared__ __align__(16) unsigned short WL[128 * 136];
    __shared__ float pw[512];

    // ---- assemble T rows, LN1, relu, bf16 -> Ab ----
    {
        int r = tid >> 1, h = tid & 1;
        const float4* m2p = (const float4*)(ws + MSG2 + ((size_t)b * 128 + r) * 128 + h * 64);
        const float4* mep = (const float4*)(ws + MSGE + (((size_t)b * 128 + r) * 128 + j) * 128 + h * 64);
        const float4* m1p = (const float4*)(ws + MSG1 + (size_t)bj * 128 + h * 64);
        const float4* mgp = (const float4*)(ws + MSGG + (size_t)b * 128 + h * 64);
        float4 vals[16];
        float s = 0.f, ssq = 0.f;
        #pragma unroll
        for (int q2 = 0; q2 < 16; q2++) {
            float4 v2 = m2p[q2], ve = mep[q2], v1 = m1p[q2], vg = mgp[q2];
            float4 v;
            v.x = v2.x + ve.x + v1.x + vg.x;
            v.y = v2.y + ve.y + v1.y + vg.y;
            v.z = v2.z + ve.z + v1.z + vg.z;
            v.w = v2.w + ve.w + v1.w + vg.w;
            vals[q2] = v;
            s += v.x + v.y + v.z + v.w;
            ssq += v.x * v.x + v.y * v.y + v.z * v.z + v.w * v.w;
        }
        s   += __shfl_xor(s, 1, 64);
        ssq += __shfl_xor(ssq, 1, 64);
        float mu = s * (1.f / 128);
        float inv = rsqrtf(ssq * (1.f / 128) - mu * mu + EPSF);
        const float4* s1p = (const float4*)(ln1s + h * 64);
        const float4* o1p = (const float4*)(ln1o + h * 64);
        unsigned* dst = (unsigned*)&Ab[r * 136 + h * 64];
        #pragma unroll
        for (int q2 = 0; q2 < 16; q2++) {
            float4 sc = s1p[q2], of = o1p[q2], v = vals[q2];
            float x0 = fmaxf(sc.x * inv * (v.x - mu) + of.x, 0.f);
            float x1 = fmaxf(sc.y * inv * (v.y - mu) + of.y, 0.f);
            float x2 = fmaxf(sc.z * inv * (v.z - mu) + of.z, 0.f);
            float x3 = fmaxf(sc.w * inv * (v.w - mu) + of.w, 0.f);
            dst[q2 * 2]     = pack2(x0, x1);
            dst[q2 * 2 + 1] = pack2(x2, x3);
        }
    }
    // stage W1^T
    #pragma unroll
    for (int q2 = 0; q2 < 8; q2++) {
        int m = q2 * 256 + tid;
        int row = m >> 4, cc = (m & 15) * 8;
        *(short8*)&WL[row * 136 + cc] = *(const short8*)&prep[W1T_OFF + m * 8];
    }
    __syncthreads();

    int lane = tid & 63, w = tid >> 6, q = lane >> 4, n = lane & 15;
    float s2v[8], o2v[8];
    #pragma unroll
    for (int t = 0; t < 8; t++) { s2v[t] = ln2s[16 * t + n]; o2v[t] = ln2o[16 * t + n]; }

    f32x4 acc[2][8];
    #pragma unroll
    for (int rt = 0; rt < 2; rt++)
        #pragma unroll
        for (int t = 0; t < 8; t++) acc[rt][t] = 0.f;

    // ---- GEMM1 ----
    #pragma unroll
    for (int ks = 0; ks < 4; ks++) {
        int k0 = ks * 32 + q * 8;
        short8 a0 = *(const short8*)&Ab[(32 * w + n) * 136 + k0];
        short8 a1 = *(const short8*)&Ab[(32 * w + 16 + n) * 136 + k0];
        #pragma unroll
        for (int t = 0; t < 8; t++) {
            short8 bt = *(const short8*)&WL[(16 * t + n) * 136 + k0];
            acc[0][t] = MFMA16(a0, bt, acc[0][t]);
            acc[1][t] = MFMA16(a1, bt, acc[1][t]);
        }
    }
    // ---- LN2 on C-fragments (rows = 32w+16rt+4q+reg) ----
    float rs[2][4], rss[2][4];
    #pragma unroll
    for (int rt = 0; rt < 2; rt++)
        #pragma unroll
        for (int reg = 0; reg < 4; reg++) {
            float s = 0.f, ssq = 0.f;
            #pragma unroll
            for (int t = 0; t < 8; t++) { float v = acc[rt][t][reg]; s += v; ssq += v * v; }
            rs[rt][reg] = s; rss[rt][reg] = ssq;
        }
    #pragma unroll
    for (int d = 1; d < 16; d <<= 1) {
        #pragma unroll
        for (int rt = 0; rt < 2; rt++)
            #pragma unroll
            for (int reg = 0; reg < 4; reg++) {
                rs[rt][reg]  += __shfl_xor(rs[rt][reg], d, 64);
                rss[rt][reg] += __shfl_xor(rss[rt][reg], d, 64);
            }
    }
    #pragma unroll
    for (int rt = 0; rt < 2; rt++)
        #pragma unroll
        for (int reg = 0; reg < 4; reg++) {
            float mu = rs[rt][reg] * (1.f / 128);
            float inv = rsqrtf(rss[rt][reg] * (1.f / 128) - mu * mu + EPSF);
            int row = 32 * w + 16 * rt + 4 * q + reg;
            #pragma unroll
            for (int t = 0; t < 8; t++) {
                float v = fmaxf(s2v[t] * inv * (acc[rt][t][reg] - mu) + o2v[t], 0.f);
                Ab[row * 136 + 16 * t + n] = f2bf(v);
            }
        }
    __syncthreads();
    // stage W2^T
    #pragma unroll
    for (int q2 = 0; q2 < 8; q2++) {
        int m = q2 * 256 + tid;
        int row = m >> 4, cc = (m & 15) * 8;
        *(short8*)&WL[row * 136 + cc] = *(const short8*)&prep[W2T_OFF + m * 8];
    }
    __syncthreads();

    // ---- GEMM2 ----
    #pragma unroll
    for (int rt = 0; rt < 2; rt++)
        #pragma unroll
        for (int t = 0; t < 8; t++) acc[rt][t] = 0.f;
    #pragma unroll
    for (int ks = 0; ks < 4; ks++) {
        int k0 = ks * 32 + q * 8;
        short8 a0 = *(const short8*)&Ab[(32 * w + n) * 136 + k0];
        short8 a1 = *(const short8*)&Ab[(32 * w + 16 + n) * 136 + k0];
        #pragma unroll
        for (int t = 0; t < 8; t++) {
            short8 bt = *(const short8*)&WL[(16 * t + n) * 136 + k0];
            acc[0][t] = MFMA16(a0, bt, acc[0][t]);
            acc[1][t] = MFMA16(a1, bt, acc[1][t]);
        }
    }
    // ---- adj mask + max over rows i ----
    float colmax[8];
    #pragma unroll
    for (int t = 0; t < 8; t++) colmax[t] = NEGF;
    #pragma unroll
    for (int rt = 0; rt < 2; rt++)
        #pragma unroll
        for (int reg = 0; reg < 4; reg++) {
            int row = 32 * w + 16 * rt + 4 * q + reg;
            bool a = rdbool(adj, ((size_t)b * 128 + row) * 128 + j, isInt);
            if (a) {
                #pragma unroll
                for (int t = 0; t < 8; t++) colmax[t] = fmaxf(colmax[t], acc[rt][t][reg]);
            }
        }
    #pragma unroll
    for (int t = 0; t < 8; t++) {
        colmax[t] = fmaxf(colmax[t], __shfl_xor(colmax[t], 16, 64));
        colmax[t] = fmaxf(colmax[t], __shfl_xor(colmax[t], 32, 64));
    }
    if (lane < 16) {
        #pragma unroll
        for (int t = 0; t < 8; t++) pw[w * 128 + 16 * t + lane] = colmax[t];
    }
    __syncthreads();
    if (tid < 128) {
        float mx = fmaxf(fmaxf(pw[tid], pw[128 + tid]), fmaxf(pw[256 + tid], pw[384 + tid]));
        out[O_MSG + (size_t)bj * 128 + tid] = mx;
    }
}

// ============================================================
// Kernel F: ret = LN(z@WU1 + msgs@WU2).  grid 512, block 128
// ============================================================
__global__ __launch_bounds__(128) void k_final(
    const float* __restrict__ ws, const float* __restrict__ WU2,
    const float* __restrict__ lnfs, const float* __restrict__ lnfo,
    float* __restrict__ out)
{
    int bn = blockIdx.x, tid = threadIdx.x;
    __shared__ float mrow[128];
    __shared__ float red[4];
    mrow[tid] = out[O_MSG + (size_t)bn * 128 + tid];
    __syncthreads();
    float y = ws[ZWU1 + (size_t)bn * 128 + tid];
    #pragma unroll 8
    for (int k = 0; k < 128; k++) y += mrow[k] * WU2[k * 128 + tid];
    float s = y, ss = y * y;
    for (int d = 1; d < 64; d <<= 1) { s += __shfl_xor(s, d, 64); ss += __shfl_xor(ss, d, 64); }
    if ((tid & 63) == 0) { red[(tid >> 6) * 2] = s; red[(tid >> 6) * 2 + 1] = ss; }
    __syncthreads();
    float S = red[0] + red[2], SS = red[1] + red[3];
    float m_ = S * (1.f / 128), v_ = SS * (1.f / 128) - m_ * m_;
    float r = rsqrtf(v_ + EPSF);
    out[O_RET + (size_t)bn * 128 + tid] = lnfs[tid] * r * (y - m_) + lnfo[tid];
}

// ============================================================
extern "C" void kernel_launch(void* const* d_in, const int* in_sizes, int n_in,
                              void* d_out, int out_size, void* d_ws, size_t ws_size,
                              hipStream_t stream)
{
    const float* z    = (const float*)d_in[0];
    const float* e    = (const float*)d_in[1];
    const float* gf   = (const float*)d_in[2];
    const void*  mask = d_in[3];
    const void*  adj  = d_in[4];
    const float* Wt1 = (const float*)d_in[5];
    const float* Wt2 = (const float*)d_in[6];
    const float* Wt3 = (const float*)d_in[7];
    const float* We1 = (const float*)d_in[8];
    const float* We2 = (const float*)d_in[9];
    const float* We3 = (const float*)d_in[10];
    const float* Wg  = (const float*)d_in[11];
    const float* Wm1 = (const float*)d_in[12];
    const float* Wm2 = (const float*)d_in[13];
    const float* Wme = (const float*)d_in[14];
    const float* Wmg = (const float*)d_in[15];
    const float* ln1s = (const float*)d_in[16];
    const float* ln1o = (const float*)d_in[17];
    const float* W1   = (const float*)d_in[18];
    const float* ln2s = (const float*)d_in[19];
    const float* ln2o = (const float*)d_in[20];
    const float* W2   = (const float*)d_in[21];
    const float* WU1  = (const float*)d_in[22];
    const float* WU2  = (const float*)d_in[23];
    const float* WU3  = (const float*)d_in[24];
    const float* lnfs = (const float*)d_in[25];
    const float* lnfo = (const float*)d_in[26];
    float* out = (float*)d_out;
    float* ws  = (float*)d_ws;
    int* flag  = (int*)(ws + FLAGOFF);
    unsigned short* prep = (unsigned short*)(ws + PREPF);

    hipLaunchKernelGGL(k_detect, dim3(1), dim3(64), 0, stream,
                       (const unsigned char*)mask, flag);
    hipLaunchKernelGGL(k_prep, dim3(208), dim3(256), 0, stream,
                       W1, W2, Wme, We1, We2, We3, prep);
    hipLaunchKernelGGL(k_proj_z, dim3(512), dim3(256), 0, stream,
                       z, mask, Wt1, Wt2, Wt3, Wm1, Wm2, WU1, ws, flag);
    hipLaunchKernelGGL(k_proj_g, dim3(4), dim3(256), 0, stream, gf, Wg, Wmg, ws);
    hipLaunchKernelGGL(k_proj_e, dim3(512), dim3(256), 0, stream,
                       e, adj, prep, ws, flag);
    hipLaunchKernelGGL(k_triplet, dim3(8, 8, 4), dim3(256), 0, stream, ws, mask, WU3, out, flag);
    hipLaunchKernelGGL(k_pair_mlp, dim3(512), dim3(256), 0, stream,
                       ws, adj, ln1s, ln1o, ln2s, ln2o, prep, out, flag);
    hipLaunchKernelGGL(k_final, dim3(512), dim3(128), 0, stream, ws, WU2, lnfs, lnfo, out);
}

// Round 4
// 242.003 us; speedup vs baseline: 1.6864x; 1.0722x over previous
//
#include <hip/hip_runtime.h>

// Problem constants
#define BN   4
#define NN   128
#define INF  256
#define EF   128
#define OUTF 128
#define EPSF 1e-5f
#define NEGF -998244352.0f   // bf16(1e9); matches the bf16-rounded np reference

typedef __attribute__((ext_vector_type(8))) short short8;
typedef __attribute__((ext_vector_type(4))) float f32x4;

#define MFMA16(a, b, c) __builtin_amdgcn_mfma_f32_16x16x32_bf16(a, b, c, 0, 0, 0)

// fp32 -> bf16 round-to-nearest-even
__device__ __forceinline__ unsigned short f2bf(float f) {
    unsigned u = __float_as_uint(f);
    u += 0x7fffu + ((u >> 16) & 1u);
    return (unsigned short)(u >> 16);
}
__device__ __forceinline__ unsigned pack2(float a, float b) {
    return (unsigned)f2bf(a) | ((unsigned)f2bf(b) << 16);
}

// ---- workspace layout (float offsets) ----
constexpr size_t TRI1 = 0;            // B*N*8   tri_1 (masked)
constexpr size_t TRI2 = 4096;
constexpr size_t TRI3 = 8192;
constexpr size_t MSG1 = 12288;        // B*N*128 msg_1 (masked)
constexpr size_t MSG2 = 77824;
constexpr size_t ZWU1 = 143360;
constexpr size_t TRIG = 208896;       // B*8
constexpr size_t MSGG = 209920;       // B*128
constexpr size_t E1T  = 210944;       // B*N*N*8  [b][j][i][c]
constexpr size_t E2T  = 735232;       // B*N*N*8  [b][k][i][c]
constexpr size_t E3N  = 1259520;      // B*N*N*8  [b][j][k][c]
constexpr size_t MSGE = 1783808;      // B*N*N*128 [b][i][j][c]
constexpr size_t FLAGOFF = 10172416;  // int flag
constexpr size_t PREPF   = 10172420;  // bf16 prepped weights (ushort region)

// prep region offsets (ushort units)
constexpr int W1T_OFF  = 0;       // [n][k] 128x128
constexpr int W2T_OFF  = 16384;
constexpr int WMET_OFF = 32768;
constexpr int WET_OFF  = 49152;   // [n][k] 32x128 packed We1|We2|We3|0

// ---- output layout (float offsets): ret, msgs, tri_msgs ----
constexpr size_t O_RET = 0;
constexpr size_t O_MSG = 65536;
constexpr size_t O_TRI = 131072;

__device__ __forceinline__ bool rdbool(const void* p, size_t idx, int isInt) {
    if (isInt) return ((const int*)p)[idx] != 0;
    return ((const unsigned char*)p)[idx] != 0;
}

// ============================================================
// k_prep: bf16 transposed weights + bool-encoding detect.
// grid 208, block 256
// ============================================================
__global__ __launch_bounds__(256) void k_prep(
    const float* __restrict__ W1, const float* __restrict__ W2, const float* __restrict__ Wme,
    const float* __restrict__ We1, const float* __restrict__ We2, const float* __restrict__ We3,
    const unsigned char* __restrict__ mask, int* __restrict__ flag,
    unsigned short* __restrict__ prep)
{
    if (blockIdx.x == 0 && threadIdx.x == 0) {
        // mask[b=0, n=1..3] always true (lengths >= 64). int32 bools -> those
        // bytes are the high bytes of mask[0][0] == 0.
        int bytes = (mask[1] | mask[2] | mask[3]) != 0;
        *flag = bytes ? 0 : 1;
    }
    int idx = blockIdx.x * 256 + threadIdx.x;
    if (idx >= 53248) return;
    if (idx < 49152) {
        const float* W = (idx < 16384) ? W1 : (idx < 32768 ? W2 : Wme);
        int i2 = idx & 16383;
        int n = i2 >> 7, k = i2 & 127;
        prep[idx] = f2bf(W[k * 128 + n]);
    } else {
        int i2 = idx - 49152;
        int n = i2 >> 7, k = i2 & 127;
        float v = 0.f;
        if (n < 8)       v = We1[k * 8 + n];
        else if (n < 16) v = We2[k * 8 + (n - 8)];
        else if (n < 24) v = We3[k * 8 + (n - 16)];
        prep[idx] = f2bf(v);
    }
}

// ============================================================
// Kernel A: z-row projections (blocks 0..511) + graph proj (512..515).
// grid 516, block 256
// ============================================================
__global__ __launch_bounds__(256) void k_proj_z(
    const float* __restrict__ z, const void* __restrict__ mask,
    const float* __restrict__ Wt1, const float* __restrict__ Wt2, const float* __restrict__ Wt3,
    const float* __restrict__ Wm1, const float* __restrict__ Wm2, const float* __restrict__ WU1,
    const float* __restrict__ g, const float* __restrict__ Wg, const float* __restrict__ Wmg,
    float* __restrict__ ws, const int* __restrict__ flagp)
{
    int tid = threadIdx.x;
    if (blockIdx.x >= 512) {       // graph_fts projections
        int b = blockIdx.x - 512;
        __shared__ float gr[128];
        if (tid < 128) gr[tid] = g[b * 128 + tid];
        __syncthreads();
        if (tid < 8) {
            float a = 0.f;
            for (int k = 0; k < 128; k++) a += gr[k] * Wg[k * 8 + tid];
            ws[TRIG + b * 8 + tid] = a;
        } else if (tid >= 128) {
            int c = tid - 128;
            float a = 0.f;
            for (int k = 0; k < 128; k++) a += gr[k] * Wmg[k * 128 + c];
            ws[MSGG + b * 128 + c] = a;
        }
        return;
    }
    int bn  = blockIdx.x;
    int isInt = *flagp;
    __shared__ float zr[INF];
    zr[tid] = z[(size_t)bn * INF + tid];
    __syncthreads();
    float mk = rdbool(mask, bn, isInt) ? 1.f : 0.f;
    for (int idx = tid; idx < 408; idx += 256) {
        const float* W; int c; size_t dst; int width; bool msk;
        if (idx < 8)        { W = Wt1; c = idx;       dst = TRI1 + (size_t)bn * 8;   width = 8;   msk = true;  }
        else if (idx < 16)  { W = Wt2; c = idx - 8;   dst = TRI2 + (size_t)bn * 8;   width = 8;   msk = true;  }
        else if (idx < 24)  { W = Wt3; c = idx - 16;  dst = TRI3 + (size_t)bn * 8;   width = 8;   msk = true;  }
        else if (idx < 152) { W = Wm1; c = idx - 24;  dst = MSG1 + (size_t)bn * 128; width = 128; msk = true;  }
        else if (idx < 280) { W = Wm2; c = idx - 152; dst = MSG2 + (size_t)bn * 128; width = 128; msk = true;  }
        else                { W = WU1; c = idx - 280; dst = ZWU1 + (size_t)bn * 128; width = 128; msk = false; }
        float acc = 0.f;
        #pragma unroll 8
        for (int k = 0; k < INF; k++) acc += zr[k] * W[k * width + c];
        ws[dst + c] = msk ? acc * mk : acc;
    }
}

// ============================================================
// Kernel B (MFMA): e projections.  block = one (b,i).  grid 512, block 256
// ============================================================
__global__ __launch_bounds__(256) void k_proj_e(
    const float* __restrict__ e, const void* __restrict__ adj,
    const unsigned short* __restrict__ prep,
    float* __restrict__ ws, const int* __restrict__ flagp)
{
    int bi = blockIdx.x;
    int b = bi >> 7, i = bi & 127;
    int tid = threadIdx.x;
    int isInt = *flagp;
    __shared__ __align__(16) unsigned short Ab[128 * 136];   // e-tile bf16
    __shared__ __align__(16) unsigned short WL[128 * 136];   // Wme^T bf16
    __shared__ __align__(16) unsigned short WeL[32 * 136];   // packed We^T bf16

    // stage e rows -> bf16
    {
        int r = tid >> 1, h = tid & 1;
        const float4* ep = (const float4*)(e + (size_t)bi * 16384 + (size_t)r * 128 + h * 64);
        unsigned* dst = (unsigned*)&Ab[r * 136 + h * 64];
        #pragma unroll
        for (int q2 = 0; q2 < 16; q2++) {
            float4 v = ep[q2];
            dst[q2 * 2]     = pack2(v.x, v.y);
            dst[q2 * 2 + 1] = pack2(v.z, v.w);
        }
    }
    // stage Wme^T
    #pragma unroll
    for (int q2 = 0; q2 < 8; q2++) {
        int m = q2 * 256 + tid;
        int row = m >> 4, cc = (m & 15) * 8;
        *(short8*)&WL[row * 136 + cc] = *(const short8*)&prep[WMET_OFF + m * 8];
    }
    // stage We^T (32 rows)
    #pragma unroll
    for (int q2 = 0; q2 < 2; q2++) {
        int m = q2 * 256 + tid;
        int row = m >> 4, cc = (m & 15) * 8;
        *(short8*)&WeL[row * 136 + cc] = *(const short8*)&prep[WET_OFF + m * 8];
    }
    __syncthreads();

    int lane = tid & 63, w = tid >> 6, q = lane >> 4, n = lane & 15;

    // GEMM: msg_e pre-mask = E @ Wme
    f32x4 acc[2][8];
    #pragma unroll
    for (int rt = 0; rt < 2; rt++)
        #pragma unroll
        for (int t = 0; t < 8; t++) acc[rt][t] = 0.f;
    #pragma unroll
    for (int ks = 0; ks < 4; ks++) {
        int k0 = ks * 32 + q * 8;
        short8 a0 = *(const short8*)&Ab[(32 * w + n) * 136 + k0];
        short8 a1 = *(const short8*)&Ab[(32 * w + 16 + n) * 136 + k0];
        #pragma unroll
        for (int t = 0; t < 8; t++) {
            short8 bt = *(const short8*)&WL[(16 * t + n) * 136 + k0];
            acc[0][t] = MFMA16(a0, bt, acc[0][t]);
            acc[1][t] = MFMA16(a1, bt, acc[1][t]);
        }
    }
    #pragma unroll
    for (int rt = 0; rt < 2; rt++)
        #pragma unroll
        for (int reg = 0; reg < 4; reg++) {
            int row = 32 * w + 16 * rt + 4 * q + reg;
            float am = rdbool(adj, (size_t)bi * 128 + row, isInt) ? 1.f : 0.f;
            float* dst = ws + MSGE + ((size_t)bi * 128 + row) * 128;
            #pragma unroll
            for (int t = 0; t < 8; t++) dst[16 * t + n] = acc[rt][t][reg] * am;
        }

    // GEMM: tri_e (packed 32 cols: We1|We2|We3|pad)
    f32x4 ac2[2][2];
    #pragma unroll
    for (int rt = 0; rt < 2; rt++)
        #pragma unroll
        for (int t = 0; t < 2; t++) ac2[rt][t] = 0.f;
    #pragma unroll
    for (int ks = 0; ks < 4; ks++) {
        int k0 = ks * 32 + q * 8;
        short8 a0 = *(const short8*)&Ab[(32 * w + n) * 136 + k0];
        short8 a1 = *(const short8*)&Ab[(32 * w + 16 + n) * 136 + k0];
        #pragma unroll
        for (int t = 0; t < 2; t++) {
            short8 bt = *(const short8*)&WeL[(16 * t + n) * 136 + k0];
            ac2[0][t] = MFMA16(a0, bt, ac2[0][t]);
            ac2[1][t] = MFMA16(a1, bt, ac2[1][t]);
        }
    }
    #pragma unroll
    for (int rt = 0; rt < 2; rt++)
        #pragma unroll
        for (int reg = 0; reg < 4; reg++) {
            int row = 32 * w + 16 * rt + 4 * q + reg;
            float v0 = ac2[rt][0][reg];
            if (n < 8) ws[E1T + ((size_t)(b * 128 + row) * 128 + i) * 8 + n] = v0;
            else       ws[E2T + ((size_t)(b * 128 + row) * 128 + i) * 8 + (n - 8)] = v0;
            if (n < 8) ws[E3N + ((size_t)bi * 128 + row) * 8 + n] = ac2[rt][1][reg];
        }
}

// ============================================================
// Kernel C: triplet max-plus pooling + relu(pooled @ WU3).
// grid (8,8,4), block 1024 (16 waves).  16x16 (j,k) tile, 4-way i-split.
// LDS: full P/Q tiles staged once; reduce region aliased onto P after use.
// ============================================================
constexpr int PSTR = 1032;   // floats; 1032 % 32 = 8, tj groups hit distinct banks
constexpr int QSTR = 1036;   // floats; 1036 % 32 = 12 -> tk*12 mod 32 is 2-way (free)

__global__ __launch_bounds__(1024) void k_triplet(
    const float* __restrict__ ws, const void* __restrict__ mask,
    const float* __restrict__ WU3, float* __restrict__ out, const int* __restrict__ flagp)
{
    int j0 = blockIdx.x * 16, k0 = blockIdx.y * 16, b = blockIdx.z;
    int tid = threadIdx.x;
    int isInt = *flagp;
    __shared__ __align__(16) float smem[16 * PSTR + 16 * QSTR];  // 33088 floats = 129.3 KB
    float* Pl = smem;               // [16][PSTR]
    float* Ql = smem + 16 * PSTR;   // [16][QSTR]
    // phase-2 aliases (P region is dead by then):
    float* red    = smem;                  // [8][1024] c-major
    float* pooled = smem + 8192;           // [256][8]
    float* WU3l   = smem + 8192 + 2048;    // [8][128]
    __shared__ unsigned char mloc[128];

    if (tid < 128) mloc[tid] = rdbool(mask, b * 128 + tid, isInt) ? 1 : 0;

    // ---- stage P = e1T[j-row] + tri1, Q = e2T[k-row]; one row per 64 threads
    {
        int r   = tid >> 6;          // 0..15
        int off = (tid & 63) * 16;   // float offset within the 1024-float row
        const float4* e1 = (const float4*)(ws + E1T + (size_t)(b * 128 + j0 + r) * 1024 + off);
        const float4* t1 = (const float4*)(ws + TRI1 + (size_t)b * 1024 + off);
        const float4* e2 = (const float4*)(ws + E2T + (size_t)(b * 128 + k0 + r) * 1024 + off);
        float* pd = Pl + r * PSTR + off;
        float* qd = Ql + r * QSTR + off;
        #pragma unroll
        for (int t = 0; t < 4; t++) {
            float4 a = e1[t], bb = t1[t], qv = e2[t];
            pd[t * 4 + 0] = a.x + bb.x; pd[t * 4 + 1] = a.y + bb.y;
            pd[t * 4 + 2] = a.z + bb.z; pd[t * 4 + 3] = a.w + bb.w;
            qd[t * 4 + 0] = qv.x; qd[t * 4 + 1] = qv.y;
            qd[t * 4 + 2] = qv.z; qd[t * 4 + 3] = qv.w;
        }
    }
    __syncthreads();

    int ic = tid >> 8;              // i-chunk 0..3 (wave-uniform)
    int tj = (tid >> 4) & 15, tk = tid & 15;
    float accM[8], accU[8];
    #pragma unroll
    for (int c = 0; c < 8; c++) { accM[c] = NEGF; accU[c] = NEGF; }
    {
        const float* pp = Pl + tj * PSTR;
        const float* qq = Ql + tk * QSTR;
        int i1 = ic * 32 + 32;
        for (int ii = ic * 32; ii < i1; ii++) {
            bool m_i = mloc[ii] != 0;   // wave-uniform
            float4 p0 = *(const float4*)(pp + ii * 8);
            float4 p1 = *(const float4*)(pp + ii * 8 + 4);
            float4 q0 = *(const float4*)(qq + ii * 8);
            float4 q1 = *(const float4*)(qq + ii * 8 + 4);
            float v[8] = { p0.x + q0.x, p0.y + q0.y, p0.z + q0.z, p0.w + q0.w,
                           p1.x + q1.x, p1.y + q1.y, p1.z + q1.z, p1.w + q1.w };
            if (m_i) {
                #pragma unroll
                for (int c = 0; c < 8; c++) accM[c] = fmaxf(accM[c], v[c]);
            } else {
                #pragma unroll
                for (int c = 0; c < 8; c++) accU[c] = fmaxf(accU[c], v[c]);
            }
        }
    }
    // pre-select per (j,k): allowed-i = all i iff mask_j | mask_k
    float sel[8];
    {
        bool all_i = (mloc[j0 + tj] | mloc[k0 + tk]) != 0;
        #pragma unroll
        for (int c = 0; c < 8; c++) sel[c] = all_i ? fmaxf(accM[c], accU[c]) : accM[c];
    }
    __syncthreads();   // P/Q reads complete; safe to overwrite with red
    #pragma unroll
    for (int c = 0; c < 8; c++) red[c * 1024 + tid] = sel[c];
    __syncthreads();

    if (tid < 256) {   // reduce 4 i-chunks + add (j,k) terms
        int rtj = tid >> 4, rtk = tid & 15;
        const float* t2 = ws + TRI2 + (size_t)(b * 128 + j0 + rtj) * 8;
        const float* t3 = ws + TRI3 + (size_t)(b * 128 + k0 + rtk) * 8;
        const float* e3 = ws + E3N + ((size_t)(b * 128 + j0 + rtj) * 128 + (k0 + rtk)) * 8;
        const float* tg = ws + TRIG + (size_t)b * 8;
        #pragma unroll
        for (int c = 0; c < 8; c++) {
            const float* rc = red + c * 1024 + tid;
            float v = fmaxf(fmaxf(rc[0], rc[256]), fmaxf(rc[512], rc[768]));
            pooled[tid * 8 + c] = v + t2[c] + t3[c] + e3[c] + tg[c];
        }
    } else if (tid < 512) {   // load WU3 concurrently
        int m = tid - 256;
        *(float4*)(WU3l + m * 4) = *(const float4*)(WU3 + m * 4);
    }
    __syncthreads();

    // ---- epilogue: relu(pooled @ WU3), float4 stores ----
    int col4 = (tid & 31) * 4;
    #pragma unroll
    for (int pass = 0; pass < 8; pass++) {
        int p = pass * 32 + (tid >> 5);
        const float* pl = pooled + p * 8;
        float4 s = { 0.f, 0.f, 0.f, 0.f };
        #pragma unroll
        for (int c = 0; c < 8; c++) {
            float pv = pl[c];
            float4 wv = *(const float4*)(WU3l + c * 128 + col4);
            s.x += pv * wv.x; s.y += pv * wv.y; s.z += pv * wv.z; s.w += pv * wv.w;
        }
        s.x = fmaxf(s.x, 0.f); s.y = fmaxf(s.y, 0.f);
        s.z = fmaxf(s.z, 0.f); s.w = fmaxf(s.w, 0.f);
        int pj = p >> 4, pk = p & 15;
        *(float4*)(out + O_TRI + ((size_t)(b * 128 + j0 + pj) * 128 + (k0 + pk)) * 128 + col4) = s;
    }
}

// ============================================================
// Kernel D (MFMA): pairwise MLP + masked max over i.
// block = one (b,j).  grid 512, block 256
// ============================================================
__global__ __launch_bounds__(256) void k_pair_mlp(
    const float* __restrict__ ws, const void* __restrict__ adj,
    const float* __restrict__ ln1s, const float* __restrict__ ln1o,
    const float* __restrict__ ln2s, const float* __restrict__ ln2o,
    const unsigned short* __restrict__ prep,
    float* __restrict__ out, const int* __restrict__ flagp)
{
    int bj = blockIdx.x;
    int b = bj >> 7, j = bj & 127;
    int tid = threadIdx.x;
    int isInt = *flagp;
    __shared__ __align__(16) unsigned short Ab[128 * 136];
    __shared__ __align__(16) unsigned short WL[128 * 136];
    __shared__ float pw[512];

    // ---- assemble T rows, LN1, relu, bf16 -> Ab ----
    {
        int r = tid >> 1, h = tid & 1;
        const float4* m2p = (const float4*)(ws + MSG2 + ((size_t)b * 128 + r) * 128 + h * 64);
        const float4* mep = (const float4*)(ws + MSGE + (((size_t)b * 128 + r) * 128 + j) * 128 + h * 64);
        const float4* m1p = (const float4*)(ws + MSG1 + (size_t)bj * 128 + h * 64);
        const float4* mgp = (const float4*)(ws + MSGG + (size_t)b * 128 + h * 64);
        float4 vals[16];
        float s = 0.f, ssq = 0.f;
        #pragma unroll
        for (int q2 = 0; q2 < 16; q2++) {
            float4 v2 = m2p[q2], ve = mep[q2], v1 = m1p[q2], vg = mgp[q2];
            float4 v;
            v.x = v2.x + ve.x + v1.x + vg.x;
            v.y = v2.y + ve.y + v1.y + vg.y;
            v.z = v2.z + ve.z + v1.z + vg.z;
            v.w = v2.w + ve.w + v1.w + vg.w;
            vals[q2] = v;
            s += v.x + v.y + v.z + v.w;
            ssq += v.x * v.x + v.y * v.y + v.z * v.z + v.w * v.w;
        }
        s   += __shfl_xor(s, 1, 64);
        ssq += __shfl_xor(ssq, 1, 64);
        float mu = s * (1.f / 128);
        float inv = rsqrtf(ssq * (1.f / 128) - mu * mu + EPSF);
        const float4* s1p = (const float4*)(ln1s + h * 64);
        const float4* o1p = (const float4*)(ln1o + h * 64);
        unsigned* dst = (unsigned*)&Ab[r * 136 + h * 64];
        #pragma unroll
        for (int q2 = 0; q2 < 16; q2++) {
            float4 sc = s1p[q2], of = o1p[q2], v = vals[q2];
            float x0 = fmaxf(sc.x * inv * (v.x - mu) + of.x, 0.f);
            float x1 = fmaxf(sc.y * inv * (v.y - mu) + of.y, 0.f);
            float x2 = fmaxf(sc.z * inv * (v.z - mu) + of.z, 0.f);
            float x3 = fmaxf(sc.w * inv * (v.w - mu) + of.w, 0.f);
            dst[q2 * 2]     = pack2(x0, x1);
            dst[q2 * 2 + 1] = pack2(x2, x3);
        }
    }
    #pragma unroll
    for (int q2 = 0; q2 < 8; q2++) {
        int m = q2 * 256 + tid;
        int row = m >> 4, cc = (m & 15) * 8;
        *(short8*)&WL[row * 136 + cc] = *(const short8*)&prep[W1T_OFF + m * 8];
    }
    __syncthreads();

    int lane = tid & 63, w = tid >> 6, q = lane >> 4, n = lane & 15;
    float s2v[8], o2v[8];
    #pragma unroll
    for (int t = 0; t < 8; t++) { s2v[t] = ln2s[16 * t + n]; o2v[t] = ln2o[16 * t + n]; }

    f32x4 acc[2][8];
    #pragma unroll
    for (int rt = 0; rt < 2; rt++)
        #pragma unroll
        for (int t = 0; t < 8; t++) acc[rt][t] = 0.f;

    // ---- GEMM1 ----
    #pragma unroll
    for (int ks = 0; ks < 4; ks++) {
        int k0 = ks * 32 + q * 8;
        short8 a0 = *(const short8*)&Ab[(32 * w + n) * 136 + k0];
        short8 a1 = *(const short8*)&Ab[(32 * w + 16 + n) * 136 + k0];
        #pragma unroll
        for (int t = 0; t < 8; t++) {
            short8 bt = *(const short8*)&WL[(16 * t + n) * 136 + k0];
            acc[0][t] = MFMA16(a0, bt, acc[0][t]);
            acc[1][t] = MFMA16(a1, bt, acc[1][t]);
        }
    }
    // ---- LN2 on C-fragments ----
    float rs[2][4], rss[2][4];
    #pragma unroll
    for (int rt = 0; rt < 2; rt++)
        #pragma unroll
        for (int reg = 0; reg < 4; reg++) {
            float s = 0.f, ssq = 0.f;
            #pragma unroll
            for (int t = 0; t < 8; t++) { float v = acc[rt][t][reg]; s += v; ssq += v * v; }
            rs[rt][reg] = s; rss[rt][reg] = ssq;
        }
    #pragma unroll
    for (int d = 1; d < 16; d <<= 1) {
        #pragma unroll
        for (int rt = 0; rt < 2; rt++)
            #pragma unroll
            for (int reg = 0; reg < 4; reg++) {
                rs[rt][reg]  += __shfl_xor(rs[rt][reg], d, 64);
                rss[rt][reg] += __shfl_xor(rss[rt][reg], d, 64);
            }
    }
    #pragma unroll
    for (int rt = 0; rt < 2; rt++)
        #pragma unroll
        for (int reg = 0; reg < 4; reg++) {
            float mu = rs[rt][reg] * (1.f / 128);
            float inv = rsqrtf(rss[rt][reg] * (1.f / 128) - mu * mu + EPSF);
            int row = 32 * w + 16 * rt + 4 * q + reg;
            #pragma unroll
            for (int t = 0; t < 8; t++) {
                float v = fmaxf(s2v[t] * inv * (acc[rt][t][reg] - mu) + o2v[t], 0.f);
                Ab[row * 136 + 16 * t + n] = f2bf(v);
            }
        }
    __syncthreads();
    #pragma unroll
    for (int q2 = 0; q2 < 8; q2++) {
        int m = q2 * 256 + tid;
        int row = m >> 4, cc = (m & 15) * 8;
        *(short8*)&WL[row * 136 + cc] = *(const short8*)&prep[W2T_OFF + m * 8];
    }
    __syncthreads();

    // ---- GEMM2 ----
    #pragma unroll
    for (int rt = 0; rt < 2; rt++)
        #pragma unroll
        for (int t = 0; t < 8; t++) acc[rt][t] = 0.f;
    #pragma unroll
    for (int ks = 0; ks < 4; ks++) {
        int k0 = ks * 32 + q * 8;
        short8 a0 = *(const short8*)&Ab[(32 * w + n) * 136 + k0];
        short8 a1 = *(const short8*)&Ab[(32 * w + 16 + n) * 136 + k0];
        #pragma unroll
        for (int t = 0; t < 8; t++) {
            short8 bt = *(const short8*)&WL[(16 * t + n) * 136 + k0];
            acc[0][t] = MFMA16(a0, bt, acc[0][t]);
            acc[1][t] = MFMA16(a1, bt, acc[1][t]);
        }
    }
    // ---- adj mask + max over rows i ----
    float colmax[8];
    #pragma unroll
    for (int t = 0; t < 8; t++) colmax[t] = NEGF;
    #pragma unroll
    for (int rt = 0; rt < 2; rt++)
        #pragma unroll
        for (int reg = 0; reg < 4; reg++) {
            int row = 32 * w + 16 * rt + 4 * q + reg;
            bool a = rdbool(adj, ((size_t)b * 128 + row) * 128 + j, isInt);
            if (a) {
                #pragma unroll
                for (int t = 0; t < 8; t++) colmax[t] = fmaxf(colmax[t], acc[rt][t][reg]);
            }
        }
    #pragma unroll
    for (int t = 0; t < 8; t++) {
        colmax[t] = fmaxf(colmax[t], __shfl_xor(colmax[t], 16, 64));
        colmax[t] = fmaxf(colmax[t], __shfl_xor(colmax[t], 32, 64));
    }
    if (lane < 16) {
        #pragma unroll
        for (int t = 0; t < 8; t++) pw[w * 128 + 16 * t + lane] = colmax[t];
    }
    __syncthreads();
    if (tid < 128) {
        float mx = fmaxf(fmaxf(pw[tid], pw[128 + tid]), fmaxf(pw[256 + tid], pw[384 + tid]));
        out[O_MSG + (size_t)bj * 128 + tid] = mx;
    }
}

// ============================================================
// Kernel F: ret = LN(z@WU1 + msgs@WU2).  grid 512, block 128
// ============================================================
__global__ __launch_bounds__(128) void k_final(
    const float* __restrict__ ws, const float* __restrict__ WU2,
    const float* __restrict__ lnfs, const float* __restrict__ lnfo,
    float* __restrict__ out)
{
    int bn = blockIdx.x, tid = threadIdx.x;
    __shared__ float mrow[128];
    __shared__ float red[4];
    mrow[tid] = out[O_MSG + (size_t)bn * 128 + tid];
    __syncthreads();
    float y = ws[ZWU1 + (size_t)bn * 128 + tid];
    #pragma unroll 8
    for (int k = 0; k < 128; k++) y += mrow[k] * WU2[k * 128 + tid];
    float s = y, ss = y * y;
    for (int d = 1; d < 64; d <<= 1) { s += __shfl_xor(s, d, 64); ss += __shfl_xor(ss, d, 64); }
    if ((tid & 63) == 0) { red[(tid >> 6) * 2] = s; red[(tid >> 6) * 2 + 1] = ss; }
    __syncthreads();
    float S = red[0] + red[2], SS = red[1] + red[3];
    float m_ = S * (1.f / 128), v_ = SS * (1.f / 128) - m_ * m_;
    float r = rsqrtf(v_ + EPSF);
    out[O_RET + (size_t)bn * 128 + tid] = lnfs[tid] * r * (y - m_) + lnfo[tid];
}

// ============================================================
extern "C" void kernel_launch(void* const* d_in, const int* in_sizes, int n_in,
                              void* d_out, int out_size, void* d_ws, size_t ws_size,
                              hipStream_t stream)
{
    const float* z    = (const float*)d_in[0];
    const float* e    = (const float*)d_in[1];
    const float* gf   = (const float*)d_in[2];
    const void*  mask = d_in[3];
    const void*  adj  = d_in[4];
    const float* Wt1 = (const float*)d_in[5];
    const float* Wt2 = (const float*)d_in[6];
    const float* Wt3 = (const float*)d_in[7];
    const float* We1 = (const float*)d_in[8];
    const float* We2 = (const float*)d_in[9];
    const float* We3 = (const float*)d_in[10];
    const float* Wg  = (const float*)d_in[11];
    const float* Wm1 = (const float*)d_in[12];
    const float* Wm2 = (const float*)d_in[13];
    const float* Wme = (const float*)d_in[14];
    const float* Wmg = (const float*)d_in[15];
    const float* ln1s = (const float*)d_in[16];
    const float* ln1o = (const float*)d_in[17];
    const float* W1   = (const float*)d_in[18];
    const float* ln2s = (const float*)d_in[19];
    const float* ln2o = (const float*)d_in[20];
    const float* W2   = (const float*)d_in[21];
    const float* WU1  = (const float*)d_in[22];
    const float* WU2  = (const float*)d_in[23];
    const float* WU3  = (const float*)d_in[24];
    const float* lnfs = (const float*)d_in[25];
    const float* lnfo = (const float*)d_in[26];
    float* out = (float*)d_out;
    float* ws  = (float*)d_ws;
    int* flag  = (int*)(ws + FLAGOFF);
    unsigned short* prep = (unsigned short*)(ws + PREPF);

    hipLaunchKernelGGL(k_prep, dim3(208), dim3(256), 0, stream,
                       W1, W2, Wme, We1, We2, We3, (const unsigned char*)mask, flag, prep);
    hipLaunchKernelGGL(k_proj_z, dim3(516), dim3(256), 0, stream,
                       z, mask, Wt1, Wt2, Wt3, Wm1, Wm2, WU1, gf, Wg, Wmg, ws, flag);
    hipLaunchKernelGGL(k_proj_e, dim3(512), dim3(256), 0, stream,
                       e, adj, prep, ws, flag);
    hipLaunchKernelGGL(k_triplet, dim3(8, 8, 4), dim3(1024), 0, stream, ws, mask, WU3, out, flag);
    hipLaunchKernelGGL(k_pair_mlp, dim3(512), dim3(256), 0, stream,
                       ws, adj, ln1s, ln1o, ln2s, ln2o, prep, out, flag);
    hipLaunchKernelGGL(k_final, dim3(512), dim3(128), 0, stream, ws, WU2, lnfs, lnfo, out);
}